// Round 4
// baseline (291.830 us; speedup 1.0000x reference)
//
#include <hip/hip_runtime.h>
#include <hip/hip_bf16.h>

typedef int   i32x4  __attribute__((ext_vector_type(4)));
typedef int   i32x8  __attribute__((ext_vector_type(8)));
typedef float f32x16 __attribute__((ext_vector_type(16)));

__device__ inline void gload_lds16(const void* g, void* l) {
  __builtin_amdgcn_global_load_lds((const __attribute__((address_space(1))) void*)g,
                                   (__attribute__((address_space(3))) void*)l, 16, 0, 0);
}
__device__ inline void gload_lds4(const void* g, void* l) {
  __builtin_amdgcn_global_load_lds((const __attribute__((address_space(1))) void*)g,
                                   (__attribute__((address_space(3))) void*)l, 4, 0, 0);
}
__device__ inline i32x8 pad8(i32x4 v) {
  i32x8 r;
  r[0] = v[0]; r[1] = v[1]; r[2] = v[2]; r[3] = v[3];
  r[4] = 0; r[5] = 0; r[6] = 0; r[7] = 0;
  return r;
}

// ---------------- Quantization: Hadamard(32) rotate + MXFP4 pack (fp4 codes + e8m0 scales) ---
// Per group of 32: FWHT rotate, v = rot*gs, scale = 2^ceil(log2(absmax/6)), codes e2m1.
// Data: row-major packed nibbles (k even = low nibble), 16B per group.
// Scales: k-step-major [step s][row][8 bytes], byte position p = h*4 + kk for block j0=2*kk+h.
__global__ __launch_bounds__(256) void quant_pack_fp4(const float* __restrict__ in,
                                                      unsigned char* __restrict__ outq,
                                                      unsigned char* __restrict__ outsc,
                                                      const float* __restrict__ gs_ptr,
                                                      int n_groups, int rows, int kg) {
  int g = blockIdx.x * 256 + threadIdx.x;
  if (g >= n_groups) return;
  const float gs = gs_ptr[0];
  int r = g / kg, j = g - r * kg;

  float t[32];
  const float4* p4 = (const float4*)(in + (size_t)g * 32);
#pragma unroll
  for (int i = 0; i < 8; ++i) {
    float4 v4 = p4[i];
    t[4 * i + 0] = v4.x; t[4 * i + 1] = v4.y;
    t[4 * i + 2] = v4.z; t[4 * i + 3] = v4.w;
  }
  // FWHT, Sylvester order (H symmetric)
#pragma unroll
  for (int s = 0; s < 5; ++s) {
    const int hh = 1 << s;
#pragma unroll
    for (int i = 0; i < 32; ++i) {
      if ((i & hh) == 0) {
        float a = t[i], b = t[i + hh];
        t[i] = a + b;
        t[i + hh] = a - b;
      }
    }
  }

  const float c = 0.17677669529663687f;  // 32^-0.5
  float v[32];
  float am = 0.0f;
#pragma unroll
  for (int i = 0; i < 32; ++i) {
    float vi = (t[i] * c) * gs;
    v[i] = vi;
    am = fmaxf(am, fabsf(vi));
  }

  float a6 = am / 6.0f;
  int ex;
  float mant = frexpf(a6, &ex);          // a6 = mant*2^ex, mant in [0.5,1)
  int e = (mant == 0.5f) ? ex - 1 : ex;  // exact ceil(log2(a6))
  if (e < -127) e = -127;
  if (e > 127) e = 127;
  float inv_s = ldexpf(1.0f, -e);        // exact power-of-two

  unsigned int dw[4] = {0u, 0u, 0u, 0u};
#pragma unroll
  for (int i = 0; i < 32; ++i) {
    float u = v[i] * inv_s;
    float au = fabsf(u);
    int idx = (au > 0.25f) + (au > 0.75f) + (au > 1.25f) + (au > 1.75f)
            + (au > 2.5f) + (au > 3.5f) + (au > 5.0f);
    int code = idx | ((u < 0.0f) ? 8 : 0);
    dw[i >> 3] |= (unsigned)code << ((i & 7) * 4);
  }
  i32x4 packed;
  packed[0] = (int)dw[0]; packed[1] = (int)dw[1];
  packed[2] = (int)dw[2]; packed[3] = (int)dw[3];
  *(i32x4*)(outq + (size_t)r * ((size_t)kg * 16) + (size_t)j * 16) = packed;

  int s = j >> 3, j0 = j & 7;
  int p = ((j0 & 1) << 2) | (j0 >> 1);   // p = h*4 + kk
  outsc[((size_t)s * rows + r) * 8 + p] = (unsigned char)(e + 127);
}

// ---------------- 256x256 8-phase MX-FP4 GEMM, C = inv*(A@B^T) + bias ----------
// 8 waves (2M x 4N), BK=256 (128B/row/tile), mfma_scale_f32_32x32x64_f8f6f4 (fmt 4 = fp4).
// Same staging geometry/swizzle/ledger as the proven bf16 8-phase skeleton; scale tiles
// (2KB/step per operand) staged with width-4 global_load_lds, all-wave symmetric counts.

#define STAGE(mb, kt, h, ldsHalf) do {                                               \
    const unsigned char* _s = (mb) + (size_t)((h)*128 + (w << 3) + (l >> 3)) * KB2   \
                      + (size_t)(kt) * 128 + (size_t)csw * 16;                       \
    gload_lds16(_s, (unsigned char*)(ldsHalf) + (w << 10));                          \
    gload_lds16(_s + ((size_t)KB2 << 6), (unsigned char*)(ldsHalf) + (w << 10) + 8192); \
  } while (0)

#define STAGE_ASC(kt, bf) gload_lds4(AscG + ((size_t)(kt) * M + brow) * 8 + (w << 8) + (l << 2), \
                                     (unsigned char*)&asc[bf][0] + (w << 8))
#define STAGE_BSC(kt, bf) gload_lds4(BscG + ((size_t)(kt) * N + bcol) * 8 + (w << 8) + (l << 2), \
                                     (unsigned char*)&bsc[bf][0] + (w << 8))

#define LOADB(bf) do {                                                               \
    const unsigned char* _bb = &lds[bf][1][0][0];                                    \
    _Pragma("unroll")                                                                \
    for (int nt = 0; nt < 2; ++nt) {                                                 \
      int row = wn * 64 + nt * 32 + (l & 31);                                        \
      int xr = row & 7;                                                              \
      _Pragma("unroll")                                                              \
      for (int kk = 0; kk < 4; ++kk)                                                 \
        bfr[nt][kk] = *(const i32x4*)(_bb + row * 128 + (((kk * 2 + h) ^ xr) << 4)); \
      sb[nt] = *(const int*)((const unsigned char*)&bsc[bf][0] + row * 8 + h * 4);   \
    } } while (0)

#define LOADA(bf, mt) do {                                                           \
    const unsigned char* _ab = &lds[bf][0][0][0];                                    \
    int row = wm * 128 + (mt) * 32 + (l & 31);                                       \
    int xr = row & 7;                                                                \
    _Pragma("unroll")                                                                \
    for (int kk = 0; kk < 4; ++kk)                                                   \
      af[kk] = *(const i32x4*)(_ab + row * 128 + (((kk * 2 + h) ^ xr) << 4));        \
    sa = *(const int*)((const unsigned char*)&asc[bf][0] + row * 8 + h * 4);         \
  } while (0)

#define MF1(mt, nt, kk)                                                              \
  acc[mt][nt] = __builtin_amdgcn_mfma_scale_f32_32x32x64_f8f6f4(                     \
      pad8(af[kk]), pad8(bfr[nt][kk]), acc[mt][nt], 4, 4, kk, sa, kk, sb[nt]);

#define MFMAQ(mt) do {                                                               \
    __builtin_amdgcn_s_setprio(1);                                                   \
    MF1(mt, 0, 0) MF1(mt, 1, 0) MF1(mt, 0, 1) MF1(mt, 1, 1)                          \
    MF1(mt, 0, 2) MF1(mt, 1, 2) MF1(mt, 0, 3) MF1(mt, 1, 3)                          \
    __builtin_amdgcn_s_setprio(0);                                                   \
  } while (0)

#define MIDSYNC() do { __builtin_amdgcn_s_barrier();                                 \
    asm volatile("s_waitcnt lgkmcnt(0)" ::: "memory");                               \
    __builtin_amdgcn_sched_barrier(0); } while (0)

#define ENDP() __builtin_amdgcn_s_barrier()
#define VM5()  asm volatile("s_waitcnt vmcnt(5)" ::: "memory")

__global__ __launch_bounds__(512, 2) void gemm256_fp4(const unsigned char* __restrict__ Aq,
                                                      const unsigned char* __restrict__ Bq,
                                                      const unsigned char* __restrict__ AscG,
                                                      const unsigned char* __restrict__ BscG,
                                                      float* __restrict__ C,
                                                      const float* __restrict__ bias,
                                                      const float* __restrict__ gsx,
                                                      const float* __restrict__ gsw,
                                                      int M, int N, int K) {
  __shared__ __align__(16) unsigned char lds[2][2][2][16384];  // [buf][A/B][half][128 rows x 128B]
  __shared__ __align__(16) unsigned char asc[2][2048];         // [buf][256 rows x 8B]
  __shared__ __align__(16) unsigned char bsc[2][2048];

  const int tid = threadIdx.x;
  const int w = tid >> 6, l = tid & 63;
  const int wm = w >> 2, wn = w & 3;
  const int h = l >> 5;
  const int csw = (l & 7) ^ (l >> 3);  // inverse-swizzled source chunk
  const int KB2 = K >> 1;              // bytes per row

  // T1: XCD-aware block swizzle (nwg = 512, divisible by 8)
  const int nwg = gridDim.x;
  int bid = blockIdx.x;
  if ((nwg & 7) == 0) bid = (bid & 7) * (nwg >> 3) + (bid >> 3);
  const int ntn = N / 256;
  const size_t brow = (size_t)(bid / ntn) * 256;
  const size_t bcol = (size_t)(bid % ntn) * 256;

  const unsigned char* Ab = Aq + brow * (size_t)KB2;
  const unsigned char* Bb = Bq + bcol * (size_t)KB2;

  f32x16 acc[4][2];
#pragma unroll
  for (int m = 0; m < 4; ++m)
#pragma unroll
    for (int n = 0; n < 2; ++n)
#pragma unroll
      for (int r = 0; r < 16; ++r) acc[m][n][r] = 0.0f;

  i32x4 af[4], bfr[2][4];
  int sa, sb[2];

  const int nkt = K / 256;       // 16
  const int niter = nkt / 2;     // 8

  // Prologue: tile0 full + tile1 B into flight; wait tile0 (+scales) only.
  STAGE(Bb, 0, 0, &lds[0][1][0][0]); STAGE_BSC(0, 0);
  STAGE(Bb, 0, 1, &lds[0][1][1][0]);
  STAGE(Ab, 0, 0, &lds[0][0][0][0]); STAGE_ASC(0, 0);
  STAGE(Ab, 0, 1, &lds[0][0][1][0]);
  STAGE(Bb, 1, 0, &lds[1][1][0][0]); STAGE_BSC(1, 1);
  STAGE(Bb, 1, 1, &lds[1][1][1][0]);
  VM5();                          // tile0 data+scales landed; tile1-B (5) in flight
  __builtin_amdgcn_s_barrier();

  for (int i = 0; i < niter; ++i) {
    const int T = 2 * i;
    const int t1 = T + 1;
    const int t2 = (T + 2 < nkt) ? T + 2 : nkt - 1;  // clamped over-stage: dead region
    const int t3 = (T + 3 < nkt) ? T + 3 : nkt - 1;

    // ph1: tile T mt0 | stage A0(t1)+Asc(t1)->buf1
    LOADB(0); LOADA(0, 0); STAGE(Ab, t1, 0, &lds[1][0][0][0]); STAGE_ASC(t1, 1);
    MIDSYNC(); MFMAQ(0); ENDP();
    // ph2: mt1 | stage A1(t1)->buf1
    LOADA(0, 1); STAGE(Ab, t1, 1, &lds[1][0][1][0]);
    MIDSYNC(); MFMAQ(1); ENDP();
    // ph3: mt2 | stage B0(t2)+Bsc(t2)->buf0 (buf0.B dead since ph1)
    LOADA(0, 2); STAGE(Bb, t2, 0, &lds[0][1][0][0]); STAGE_BSC(t2, 0);
    MIDSYNC(); MFMAQ(2); ENDP();
    // ph4: mt3 | stage B1(t2)->buf0 | vmcnt: tile t1 (data+scales) fully landed
    LOADA(0, 3); STAGE(Bb, t2, 1, &lds[0][1][1][0]);
    MIDSYNC(); MFMAQ(3); VM5(); ENDP();

    // ph5: tile t1 mt0 | stage A0(t2)+Asc(t2)->buf0 (buf0.A dead since ph4)
    LOADB(1); LOADA(1, 0); STAGE(Ab, t2, 0, &lds[0][0][0][0]); STAGE_ASC(t2, 0);
    MIDSYNC(); MFMAQ(0); ENDP();
    // ph6: mt1 | stage A1(t2)->buf0
    LOADA(1, 1); STAGE(Ab, t2, 1, &lds[0][0][1][0]);
    MIDSYNC(); MFMAQ(1); ENDP();
    // ph7: mt2 | stage B0(t3)+Bsc(t3)->buf1 (buf1.B dead since ph5)
    LOADA(1, 2); STAGE(Bb, t3, 0, &lds[1][1][0][0]); STAGE_BSC(t3, 1);
    MIDSYNC(); MFMAQ(2); ENDP();
    // ph8: mt3 | stage B1(t3)->buf1 | vmcnt: tile t2 (data+scales) fully landed
    LOADA(1, 3); STAGE(Bb, t3, 1, &lds[1][1][1][0]);
    MIDSYNC(); MFMAQ(3); VM5(); ENDP();
  }

  const float inv = 1.0f / (gsx[0] * gsw[0]);
#pragma unroll
  for (int nt = 0; nt < 2; ++nt) {
    const int col = (int)bcol + wn * 64 + nt * 32 + (l & 31);
    const float bv = bias[col];
#pragma unroll
    for (int mt = 0; mt < 4; ++mt) {
      const size_t rbase = brow + (size_t)(wm * 128 + mt * 32 + 4 * h);
#pragma unroll
      for (int r = 0; r < 16; ++r) {
        const size_t row = rbase + (r & 3) + 8 * (r >> 2);
        C[row * (size_t)N + col] = acc[mt][nt][r] * inv + bv;
      }
    }
  }
}

extern "C" void kernel_launch(void* const* d_in, const int* in_sizes, int n_in,
                              void* d_out, int out_size, void* d_ws, size_t ws_size,
                              hipStream_t stream) {
  const float* x    = (const float*)d_in[0];
  const float* wgt  = (const float*)d_in[1];
  const float* bias = (const float*)d_in[2];
  const float* wgs  = (const float*)d_in[4];
  const float* ags  = (const float*)d_in[5];

  const int N = in_sizes[2];            // 4096
  const int K = in_sizes[1] / N;        // 4096
  const int M = in_sizes[0] / K;        // 8192
  const int kg = K / 32;                // 128

  unsigned char* aq  = (unsigned char*)d_ws;
  unsigned char* bq  = aq + (size_t)M * (K / 2);
  unsigned char* asc = bq + (size_t)N * (K / 2);
  unsigned char* bsc = asc + (size_t)M * kg;

  const int xg = in_sizes[0] / 32;
  const int wg = in_sizes[1] / 32;
  quant_pack_fp4<<<dim3((xg + 255) / 256), dim3(256), 0, stream>>>(x, aq, asc, ags, xg, M, kg);
  quant_pack_fp4<<<dim3((wg + 255) / 256), dim3(256), 0, stream>>>(wgt, bq, bsc, wgs, wg, N, kg);

  dim3 grid((M / 256) * (N / 256));
  gemm256_fp4<<<grid, dim3(512), 0, stream>>>(aq, bq, asc, bsc, (float*)d_out, bias,
                                              ags, wgs, M, N, K);
}

// Round 5
// 160.431 us; speedup vs baseline: 1.8190x; 1.8190x over previous
//
#include <hip/hip_runtime.h>
#include <hip/hip_bf16.h>

typedef int   i32x4  __attribute__((ext_vector_type(4)));
typedef int   i32x8  __attribute__((ext_vector_type(8)));
typedef float f32x16 __attribute__((ext_vector_type(16)));

__device__ inline void gload_lds16(const void* g, void* l) {
  __builtin_amdgcn_global_load_lds((const __attribute__((address_space(1))) void*)g,
                                   (__attribute__((address_space(3))) void*)l, 16, 0, 0);
}
__device__ inline void gload_lds4(const void* g, void* l) {
  __builtin_amdgcn_global_load_lds((const __attribute__((address_space(1))) void*)g,
                                   (__attribute__((address_space(3))) void*)l, 4, 0, 0);
}
__device__ inline i32x8 pad8(i32x4 v) {
  i32x8 r;
  r[0] = v[0]; r[1] = v[1]; r[2] = v[2]; r[3] = v[3];
  r[4] = 0; r[5] = 0; r[6] = 0; r[7] = 0;
  return r;
}

// ---------------- Quantization: Hadamard(32) rotate + MXFP4 pack (fp4 codes + e8m0 scales) ---
__global__ __launch_bounds__(256) void quant_pack_fp4(const float* __restrict__ in,
                                                      unsigned char* __restrict__ outq,
                                                      unsigned char* __restrict__ outsc,
                                                      const float* __restrict__ gs_ptr,
                                                      int n_groups, int rows, int kg) {
  int g = blockIdx.x * 256 + threadIdx.x;
  if (g >= n_groups) return;
  const float gs = gs_ptr[0];
  int r = g / kg, j = g - r * kg;

  float t[32];
  const float4* p4 = (const float4*)(in + (size_t)g * 32);
#pragma unroll
  for (int i = 0; i < 8; ++i) {
    float4 v4 = p4[i];
    t[4 * i + 0] = v4.x; t[4 * i + 1] = v4.y;
    t[4 * i + 2] = v4.z; t[4 * i + 3] = v4.w;
  }
#pragma unroll
  for (int s = 0; s < 5; ++s) {
    const int hh = 1 << s;
#pragma unroll
    for (int i = 0; i < 32; ++i) {
      if ((i & hh) == 0) {
        float a = t[i], b = t[i + hh];
        t[i] = a + b;
        t[i + hh] = a - b;
      }
    }
  }

  const float c = 0.17677669529663687f;  // 32^-0.5
  float v[32];
  float am = 0.0f;
#pragma unroll
  for (int i = 0; i < 32; ++i) {
    float vi = (t[i] * c) * gs;
    v[i] = vi;
    am = fmaxf(am, fabsf(vi));
  }

  float a6 = am / 6.0f;
  int ex;
  float mant = frexpf(a6, &ex);
  int e = (mant == 0.5f) ? ex - 1 : ex;  // exact ceil(log2(a6))
  if (e < -127) e = -127;
  if (e > 127) e = 127;
  float inv_s = ldexpf(1.0f, -e);

  unsigned int dw[4] = {0u, 0u, 0u, 0u};
#pragma unroll
  for (int i = 0; i < 32; ++i) {
    float u = v[i] * inv_s;
    float au = fabsf(u);
    int idx = (au > 0.25f) + (au > 0.75f) + (au > 1.25f) + (au > 1.75f)
            + (au > 2.5f) + (au > 3.5f) + (au > 5.0f);
    int code = idx | ((u < 0.0f) ? 8 : 0);
    dw[i >> 3] |= (unsigned)code << ((i & 7) * 4);
  }
  i32x4 packed;
  packed[0] = (int)dw[0]; packed[1] = (int)dw[1];
  packed[2] = (int)dw[2]; packed[3] = (int)dw[3];
  *(i32x4*)(outq + (size_t)r * ((size_t)kg * 16) + (size_t)j * 16) = packed;

  int s = j >> 3, j0 = j & 7;
  int p = ((j0 & 1) << 2) | (j0 >> 1);   // p = h*4 + kk
  outsc[((size_t)s * rows + r) * 8 + p] = (unsigned char)(e + 127);
}

// ---------------- 128x128 MX-FP4 GEMM, 2 blocks/CU, C = inv*(A@B^T) + bias ----------
// 4 waves (2M x 2N), BK=256 (128B rows -> proven conflict-free swizzle), dbuf.
// 2 phases per K-tile: {ph_a: LOADB+LOADA(0) || stage A(t+1)+ASC} {ph_b: LOADA(1) ||
// stage B(t+2)+BSC, vmcnt(5)}. LDS 68 KiB -> 2 blocks/CU for TLP over vmcnt stalls.

#define STAGE(mb, kt, h, ldsHalf) do {                                               \
    const unsigned char* _s = (mb) + (size_t)((h)*64 + (w << 3) + (l >> 3)) * KB2    \
                      + (size_t)(kt) * 128 + (size_t)csw * 16;                       \
    gload_lds16(_s, (unsigned char*)(ldsHalf) + (w << 10));                          \
    gload_lds16(_s + ((size_t)KB2 << 5), (unsigned char*)(ldsHalf) + (w << 10) + 4096); \
  } while (0)

#define STAGE_ASC(kt, bf) gload_lds4(AscG + ((size_t)(kt) * M + brow) * 8 + (tid << 2), \
                                     (unsigned char*)&asc[bf][0] + (w << 8))
#define STAGE_BSC(kt, bf) gload_lds4(BscG + ((size_t)(kt) * N + bcol) * 8 + (tid << 2), \
                                     (unsigned char*)&bsc[bf][0] + (w << 8))

#define LOADB(bf) do {                                                               \
    const unsigned char* _bb = &lds[bf][1][0][0];                                    \
    _Pragma("unroll")                                                                \
    for (int nt = 0; nt < 2; ++nt) {                                                 \
      int row = wn * 64 + nt * 32 + (l & 31);                                        \
      int xr = row & 7;                                                              \
      _Pragma("unroll")                                                              \
      for (int kk = 0; kk < 4; ++kk)                                                 \
        bfr[nt][kk] = *(const i32x4*)(_bb + row * 128 + (((kk * 2 + h) ^ xr) << 4)); \
      sb[nt] = *(const int*)((const unsigned char*)&bsc[bf][0] + row * 8 + h * 4);   \
    } } while (0)

#define LOADA(bf, mt) do {                                                           \
    const unsigned char* _ab = &lds[bf][0][0][0];                                    \
    int row = wm * 64 + (mt) * 32 + (l & 31);                                        \
    int xr = row & 7;                                                                \
    _Pragma("unroll")                                                                \
    for (int kk = 0; kk < 4; ++kk)                                                   \
      af[kk] = *(const i32x4*)(_ab + row * 128 + (((kk * 2 + h) ^ xr) << 4));        \
    sa = *(const int*)((const unsigned char*)&asc[bf][0] + row * 8 + h * 4);         \
  } while (0)

#define MF1(mt, nt, kk)                                                              \
  acc[mt][nt] = __builtin_amdgcn_mfma_scale_f32_32x32x64_f8f6f4(                     \
      pad8(af[kk]), pad8(bfr[nt][kk]), acc[mt][nt], 4, 4, kk, sa, kk, sb[nt]);

#define MFMAQ(mt) do {                                                               \
    __builtin_amdgcn_s_setprio(1);                                                   \
    MF1(mt, 0, 0) MF1(mt, 1, 0) MF1(mt, 0, 1) MF1(mt, 1, 1)                          \
    MF1(mt, 0, 2) MF1(mt, 1, 2) MF1(mt, 0, 3) MF1(mt, 1, 3)                          \
    __builtin_amdgcn_s_setprio(0);                                                   \
  } while (0)

#define MIDSYNC() do { __builtin_amdgcn_s_barrier();                                 \
    asm volatile("s_waitcnt lgkmcnt(0)" ::: "memory");                               \
    __builtin_amdgcn_sched_barrier(0); } while (0)

#define ENDP() __builtin_amdgcn_s_barrier()
#define VM5()  asm volatile("s_waitcnt vmcnt(5)" ::: "memory")

__global__ __launch_bounds__(256, 2) void gemm128_fp4(const unsigned char* __restrict__ Aq,
                                                      const unsigned char* __restrict__ Bq,
                                                      const unsigned char* __restrict__ AscG,
                                                      const unsigned char* __restrict__ BscG,
                                                      float* __restrict__ C,
                                                      const float* __restrict__ bias,
                                                      const float* __restrict__ gsx,
                                                      const float* __restrict__ gsw,
                                                      int M, int N, int K) {
  __shared__ __align__(16) unsigned char lds[2][2][2][8192];  // [buf][A/B][half][64 rows x 128B]
  __shared__ __align__(16) unsigned char asc[2][1024];        // [buf][128 rows x 8B]
  __shared__ __align__(16) unsigned char bsc[2][1024];

  const int tid = threadIdx.x;
  const int w = tid >> 6, l = tid & 63;
  const int wm = w >> 1, wn = w & 1;
  const int h = l >> 5;
  const int csw = (l & 7) ^ (l >> 3);  // inverse-swizzled source chunk (row&7 == l>>3 mod 8)
  const int KB2 = K >> 1;              // bytes per row

  // T1: XCD-aware block swizzle (nwg = 2048, divisible by 8)
  const int nwg = gridDim.x;
  int bid = blockIdx.x;
  if ((nwg & 7) == 0) bid = (bid & 7) * (nwg >> 3) + (bid >> 3);
  const int ntn = N / 128;
  const size_t brow = (size_t)(bid / ntn) * 128;
  const size_t bcol = (size_t)(bid % ntn) * 128;

  const unsigned char* Ab = Aq + brow * (size_t)KB2;
  const unsigned char* Bb = Bq + bcol * (size_t)KB2;

  f32x16 acc[2][2];
#pragma unroll
  for (int m = 0; m < 2; ++m)
#pragma unroll
    for (int n = 0; n < 2; ++n)
#pragma unroll
      for (int r = 0; r < 16; ++r) acc[m][n][r] = 0.0f;

  i32x4 af[4], bfr[2][4];
  int sa, sb[2];

  const int nkt = K / 256;       // 16

  // Prologue: A(0)+ASC(0), B(0)+BSC(0), B(1)+BSC(1) = 15 loads; keep B(1) set (5) in flight.
  STAGE(Ab, 0, 0, &lds[0][0][0][0]); STAGE(Ab, 0, 1, &lds[0][0][1][0]); STAGE_ASC(0, 0);
  STAGE(Bb, 0, 0, &lds[0][1][0][0]); STAGE(Bb, 0, 1, &lds[0][1][1][0]); STAGE_BSC(0, 0);
  STAGE(Bb, 1, 0, &lds[1][1][0][0]); STAGE(Bb, 1, 1, &lds[1][1][1][0]); STAGE_BSC(1, 1);
  VM5();
  __builtin_amdgcn_s_barrier();

  for (int t = 0; t < nkt; ++t) {
    const int p = t & 1;
    const int ta = (t + 1 < nkt) ? t + 1 : nkt - 1;  // clamped over-stage: dead region
    const int tb = (t + 2 < nkt) ? t + 2 : nkt - 1;

    // ph_a: mt0 | stage A(t+1)+ASC -> buf[1-p] (buf[1-p].A dead since ph_b(t-1))
    LOADB(p); LOADA(p, 0);
    STAGE(Ab, ta, 0, &lds[1 - p][0][0][0]);
    STAGE(Ab, ta, 1, &lds[1 - p][0][1][0]);
    STAGE_ASC(ta, 1 - p);
    MIDSYNC(); MFMAQ(0); ENDP();

    // ph_b: mt1 | stage B(t+2)+BSC -> buf[p] (buf[p].B dead since ph_a) | vmcnt:
    // drains A(t+1)+B(t+1), keeps B(t+2) set (5) in flight.
    LOADA(p, 1);
    STAGE(Bb, tb, 0, &lds[p][1][0][0]);
    STAGE(Bb, tb, 1, &lds[p][1][1][0]);
    STAGE_BSC(tb, p);
    MIDSYNC(); MFMAQ(1); VM5(); ENDP();
  }

  const float inv = 1.0f / (gsx[0] * gsw[0]);
#pragma unroll
  for (int nt = 0; nt < 2; ++nt) {
    const int col = (int)bcol + wn * 64 + nt * 32 + (l & 31);
    const float bv = bias[col];
#pragma unroll
    for (int mt = 0; mt < 2; ++mt) {
      const size_t rbase = brow + (size_t)(wm * 64 + mt * 32 + 4 * h);
#pragma unroll
      for (int r = 0; r < 16; ++r) {
        const size_t row = rbase + (r & 3) + 8 * (r >> 2);
        C[row * (size_t)N + col] = acc[mt][nt][r] * inv + bv;
      }
    }
  }
}

extern "C" void kernel_launch(void* const* d_in, const int* in_sizes, int n_in,
                              void* d_out, int out_size, void* d_ws, size_t ws_size,
                              hipStream_t stream) {
  const float* x    = (const float*)d_in[0];
  const float* wgt  = (const float*)d_in[1];
  const float* bias = (const float*)d_in[2];
  const float* wgs  = (const float*)d_in[4];
  const float* ags  = (const float*)d_in[5];

  const int N = in_sizes[2];            // 4096
  const int K = in_sizes[1] / N;        // 4096
  const int M = in_sizes[0] / K;        // 8192
  const int kg = K / 32;                // 128

  unsigned char* aq  = (unsigned char*)d_ws;
  unsigned char* bq  = aq + (size_t)M * (K / 2);
  unsigned char* asc = bq + (size_t)N * (K / 2);
  unsigned char* bsc = asc + (size_t)M * kg;

  const int xg = in_sizes[0] / 32;
  const int wg = in_sizes[1] / 32;
  quant_pack_fp4<<<dim3((xg + 255) / 256), dim3(256), 0, stream>>>(x, aq, asc, ags, xg, M, kg);
  quant_pack_fp4<<<dim3((wg + 255) / 256), dim3(256), 0, stream>>>(wgt, bq, bsc, wgs, wg, N, kg);

  dim3 grid((M / 128) * (N / 128));
  gemm128_fp4<<<grid, dim3(256), 0, stream>>>(aq, bq, asc, bsc, (float*)d_out, bias,
                                              ags, wgs, M, N, K);
}

// Round 6
// 155.859 us; speedup vs baseline: 1.8724x; 1.0293x over previous
//
#include <hip/hip_runtime.h>
#include <hip/hip_bf16.h>

typedef int   i32x4  __attribute__((ext_vector_type(4)));
typedef int   i32x8  __attribute__((ext_vector_type(8)));
typedef float f32x16 __attribute__((ext_vector_type(16)));

__device__ inline void gload_lds16(const void* g, void* l) {
  __builtin_amdgcn_global_load_lds((const __attribute__((address_space(1))) void*)g,
                                   (__attribute__((address_space(3))) void*)l, 16, 0, 0);
}
__device__ inline void gload_lds4(const void* g, void* l) {
  __builtin_amdgcn_global_load_lds((const __attribute__((address_space(1))) void*)g,
                                   (__attribute__((address_space(3))) void*)l, 4, 0, 0);
}
__device__ inline i32x8 pad8(i32x4 v) {
  i32x8 r;
  r[0] = v[0]; r[1] = v[1]; r[2] = v[2]; r[3] = v[3];
  r[4] = 0; r[5] = 0; r[6] = 0; r[7] = 0;
  return r;
}

// ---------------- Quantization: Hadamard(32) rotate + MXFP4 pack (fp4 codes + e8m0 scales) ---
// NOTE: launched with n_groups % 256 == 0 (exact grid), so no tail guard needed.
__global__ __launch_bounds__(256) void quant_pack_fp4(const float* __restrict__ in,
                                                      unsigned char* __restrict__ outq,
                                                      unsigned char* __restrict__ outsc,
                                                      const float* __restrict__ gs_ptr,
                                                      int n_groups, int rows, int kg) {
  int g = blockIdx.x * 256 + threadIdx.x;
  const float gs = gs_ptr[0];
  int r = g / kg, j = g - r * kg;

  float t[32];
  const float4* p4 = (const float4*)(in + (size_t)g * 32);
#pragma unroll
  for (int i = 0; i < 8; ++i) {
    float4 v4 = p4[i];
    t[4 * i + 0] = v4.x; t[4 * i + 1] = v4.y;
    t[4 * i + 2] = v4.z; t[4 * i + 3] = v4.w;
  }
#pragma unroll
  for (int s = 0; s < 5; ++s) {
    const int hh = 1 << s;
#pragma unroll
    for (int i = 0; i < 32; ++i) {
      if ((i & hh) == 0) {
        float a = t[i], b = t[i + hh];
        t[i] = a + b;
        t[i + hh] = a - b;
      }
    }
  }

  const float c = 0.17677669529663687f;  // 32^-0.5
  float v[32];
  float am = 0.0f;
#pragma unroll
  for (int i = 0; i < 32; ++i) {
    float vi = (t[i] * c) * gs;
    v[i] = vi;
    am = fmaxf(am, fabsf(vi));
  }

  float a6 = am / 6.0f;
  int ex;
  float mant = frexpf(a6, &ex);
  int e = (mant == 0.5f) ? ex - 1 : ex;  // exact ceil(log2(a6))
  if (e < -127) e = -127;
  if (e > 127) e = 127;
  float inv_s = ldexpf(1.0f, -e);

  unsigned int dw[4] = {0u, 0u, 0u, 0u};
#pragma unroll
  for (int i = 0; i < 32; ++i) {
    float u = v[i] * inv_s;
    float au = fabsf(u);
    int idx = (au > 0.25f) + (au > 0.75f) + (au > 1.25f) + (au > 1.75f)
            + (au > 2.5f) + (au > 3.5f) + (au > 5.0f);
    int code = idx | ((u < 0.0f) ? 8 : 0);
    dw[i >> 3] |= (unsigned)code << ((i & 7) * 4);
  }
  i32x4 packed;
  packed[0] = (int)dw[0]; packed[1] = (int)dw[1];
  packed[2] = (int)dw[2]; packed[3] = (int)dw[3];
  *(i32x4*)(outq + (size_t)r * ((size_t)kg * 16) + (size_t)j * 16) = packed;

  // scale byte for group: [step s][row][8B], byte p = h*4 + kk (j0 = 2*kk + h)
  int s = j >> 3, j0 = j & 7;
  int p = ((j0 & 1) << 2) | (j0 >> 1);
  if (kg == 128) {
    // block spans exactly 2 rows x 16 steps -> stage 256B in LDS, write 16B words
    __shared__ unsigned char sl[256];  // [16 steps][2 rows][8B]
    sl[(s << 4) | ((r & 1) << 3) | p] = (unsigned char)(e + 127);
    __syncthreads();
    if (threadIdx.x < 64) {
      int si = threadIdx.x >> 2, wd = threadIdx.x & 3;
      unsigned int vv = *(const unsigned int*)&sl[(si << 4) | (wd << 2)];
      size_t r0 = (size_t)blockIdx.x * 2;
      *(unsigned int*)(outsc + ((size_t)si * rows + r0) * 8 + (wd << 2)) = vv;
    }
  } else {
    outsc[((size_t)s * rows + r) * 8 + p] = (unsigned char)(e + 127);
  }
}

// ---------------- 128x128 MX-FP4 GEMM, 2 blocks/CU, C = inv*(A@B^T) + bias ----------
// 4 waves (2M x 2N), BK=256, dbuf; both A and B staged 2 tiles ahead into the
// buffer whose reads were issued before the preceding barrier (post-MIDSYNC issue).
// Ledger: 5 loads per STAGE-set, queue [B(t+1)^5, A(t+1)^5, B(t+2)^5, A(t+2)^5]
// at end-of-tile wait -> vmcnt(10) drains exactly through A(t+1).

#define STAGE(mb, kt, h, ldsHalf) do {                                               \
    const unsigned char* _s = (mb) + (size_t)((h)*64 + (w << 3) + (l >> 3)) * KB2    \
                      + (size_t)(kt) * 128 + (size_t)csw * 16;                       \
    gload_lds16(_s, (unsigned char*)(ldsHalf) + (w << 10));                          \
    gload_lds16(_s + ((size_t)KB2 << 5), (unsigned char*)(ldsHalf) + (w << 10) + 4096); \
  } while (0)

#define STAGE_ASC(kt, bf) gload_lds4(AscG + ((size_t)(kt) * M + brow) * 8 + (tid << 2), \
                                     (unsigned char*)&asc[bf][0] + (w << 8))
#define STAGE_BSC(kt, bf) gload_lds4(BscG + ((size_t)(kt) * N + bcol) * 8 + (tid << 2), \
                                     (unsigned char*)&bsc[bf][0] + (w << 8))

#define LOADB(bf) do {                                                               \
    const unsigned char* _bb = &lds[bf][1][0][0];                                    \
    _Pragma("unroll")                                                                \
    for (int nt = 0; nt < 2; ++nt) {                                                 \
      int row = wn * 64 + nt * 32 + (l & 31);                                        \
      int xr = row & 7;                                                              \
      _Pragma("unroll")                                                              \
      for (int kk = 0; kk < 4; ++kk)                                                 \
        bfr[nt][kk] = *(const i32x4*)(_bb + row * 128 + (((kk * 2 + h) ^ xr) << 4)); \
      sb[nt] = *(const int*)((const unsigned char*)&bsc[bf][0] + row * 8 + h * 4);   \
    } } while (0)

#define LOADA(bf, mt) do {                                                           \
    const unsigned char* _ab = &lds[bf][0][0][0];                                    \
    int row = wm * 64 + (mt) * 32 + (l & 31);                                        \
    int xr = row & 7;                                                                \
    _Pragma("unroll")                                                                \
    for (int kk = 0; kk < 4; ++kk)                                                   \
      af[kk] = *(const i32x4*)(_ab + row * 128 + (((kk * 2 + h) ^ xr) << 4));        \
    sa = *(const int*)((const unsigned char*)&asc[bf][0] + row * 8 + h * 4);         \
  } while (0)

#define MF1(mt, nt, kk)                                                              \
  acc[mt][nt] = __builtin_amdgcn_mfma_scale_f32_32x32x64_f8f6f4(                     \
      pad8(af[kk]), pad8(bfr[nt][kk]), acc[mt][nt], 4, 4, kk, sa, kk, sb[nt]);

#define MFMAQ(mt) do {                                                               \
    __builtin_amdgcn_s_setprio(1);                                                   \
    MF1(mt, 0, 0) MF1(mt, 1, 0) MF1(mt, 0, 1) MF1(mt, 1, 1)                          \
    MF1(mt, 0, 2) MF1(mt, 1, 2) MF1(mt, 0, 3) MF1(mt, 1, 3)                          \
    __builtin_amdgcn_s_setprio(0);                                                   \
  } while (0)

#define MIDSYNC() do { __builtin_amdgcn_s_barrier();                                 \
    asm volatile("s_waitcnt lgkmcnt(0)" ::: "memory");                               \
    __builtin_amdgcn_sched_barrier(0); } while (0)

#define ENDP() __builtin_amdgcn_s_barrier()
#define VM10() asm volatile("s_waitcnt vmcnt(10)" ::: "memory")

__global__ __launch_bounds__(256, 2) void gemm128_fp4(const unsigned char* __restrict__ Aq,
                                                      const unsigned char* __restrict__ Bq,
                                                      const unsigned char* __restrict__ AscG,
                                                      const unsigned char* __restrict__ BscG,
                                                      float* __restrict__ C,
                                                      const float* __restrict__ bias,
                                                      const float* __restrict__ gsx,
                                                      const float* __restrict__ gsw,
                                                      int M, int N, int K) {
  __shared__ __align__(16) unsigned char lds[2][2][2][8192];  // [buf][A/B][half][64 rows x 128B]
  __shared__ __align__(16) unsigned char asc[2][1024];        // [buf][128 rows x 8B]
  __shared__ __align__(16) unsigned char bsc[2][1024];

  const int tid = threadIdx.x;
  const int w = tid >> 6, l = tid & 63;
  const int wm = w >> 1, wn = w & 1;
  const int h = l >> 5;
  const int csw = (l & 7) ^ (l >> 3);  // inverse-swizzled source chunk
  const int KB2 = K >> 1;              // bytes per row

  // T1 + L2 supertiling: XCD gets a contiguous tile-row band; within it, 8x8
  // supertiles so the ~64 concurrent blocks/XCD share ~4MB of A+B panels (= L2).
  const int ntn = N >> 7;
  const int nwg = gridDim.x;
  int r_t, c_t;
  {
    int bid = blockIdx.x;
    if ((nwg & 7) == 0) {
      int x = bid & 7, o = bid >> 3, cpx = nwg >> 3;
      int rpx = cpx / ntn;  // tile-rows per XCD
      if ((ntn & 7) == 0 && rpx > 0 && (cpx % ntn) == 0) {
        int g8 = o & 7, rr = (o >> 3) % rpx, ss = o / (8 * rpx);
        r_t = x * rpx + rr;
        c_t = ss * 8 + g8;
      } else {
        int lin = x * cpx + o;
        r_t = lin / ntn; c_t = lin % ntn;
      }
    } else {
      r_t = bid / ntn; c_t = bid % ntn;
    }
  }
  const size_t brow = (size_t)r_t * 128;
  const size_t bcol = (size_t)c_t * 128;

  const unsigned char* Ab = Aq + brow * (size_t)KB2;
  const unsigned char* Bb = Bq + bcol * (size_t)KB2;

  f32x16 acc[2][2];
#pragma unroll
  for (int m = 0; m < 2; ++m)
#pragma unroll
    for (int n = 0; n < 2; ++n)
#pragma unroll
      for (int r = 0; r < 16; ++r) acc[m][n][r] = 0.0f;

  i32x4 af[4], bfr[2][4];
  int sa, sb[2];

  const int nkt = K / 256;       // 16

  // Prologue: issue order [A0,B0,B1,A1] (5 loads each) -> after vmcnt(10):
  // A0,B0 landed; in-flight queue = [B1^5, A1^5] = steady state entering tile 0.
  STAGE(Ab, 0, 0, &lds[0][0][0][0]); STAGE(Ab, 0, 1, &lds[0][0][1][0]); STAGE_ASC(0, 0);
  STAGE(Bb, 0, 0, &lds[0][1][0][0]); STAGE(Bb, 0, 1, &lds[0][1][1][0]); STAGE_BSC(0, 0);
  STAGE(Bb, 1, 0, &lds[1][1][0][0]); STAGE(Bb, 1, 1, &lds[1][1][1][0]); STAGE_BSC(1, 1);
  STAGE(Ab, 1, 0, &lds[1][0][0][0]); STAGE(Ab, 1, 1, &lds[1][0][1][0]); STAGE_ASC(1, 1);
  VM10();
  __builtin_amdgcn_s_barrier();

  for (int t = 0; t < nkt; ++t) {
    const int p = t & 1;
    const int t2 = (t + 2 < nkt) ? t + 2 : nkt - 1;  // clamped over-stage: dead region

    // ph_a: reads of buf[p] B + A(mt0) issued pre-barrier; then stage B(t+2)->buf[p].B
    // (all its readers issued before the barrier; DMA lands >=500cy later).
    LOADB(p); LOADA(p, 0);
    MIDSYNC();
    STAGE(Bb, t2, 0, &lds[p][1][0][0]);
    STAGE(Bb, t2, 1, &lds[p][1][1][0]);
    STAGE_BSC(t2, p);
    MFMAQ(0);
    ENDP();

    // ph_b: A(mt1) reads issued pre-barrier; stage A(t+2)->buf[p].A; counted wait.
    LOADA(p, 1);
    MIDSYNC();
    STAGE(Ab, t2, 0, &lds[p][0][0][0]);
    STAGE(Ab, t2, 1, &lds[p][0][1][0]);
    STAGE_ASC(t2, p);
    MFMAQ(1);
    VM10();   // drains through A(t+1); keeps [B(t+2)^5, A(t+2)^5] in flight
    ENDP();
  }

  const float inv = 1.0f / (gsx[0] * gsw[0]);
#pragma unroll
  for (int nt = 0; nt < 2; ++nt) {
    const int col = (int)bcol + wn * 64 + nt * 32 + (l & 31);
    const float bv = bias[col];
#pragma unroll
    for (int mt = 0; mt < 2; ++mt) {
      const size_t rbase = brow + (size_t)(wm * 64 + mt * 32 + 4 * h);
#pragma unroll
      for (int r = 0; r < 16; ++r) {
        const size_t row = rbase + (r & 3) + 8 * (r >> 2);
        C[row * (size_t)N + col] = acc[mt][nt][r] * inv + bv;
      }
    }
  }
}

extern "C" void kernel_launch(void* const* d_in, const int* in_sizes, int n_in,
                              void* d_out, int out_size, void* d_ws, size_t ws_size,
                              hipStream_t stream) {
  const float* x    = (const float*)d_in[0];
  const float* wgt  = (const float*)d_in[1];
  const float* bias = (const float*)d_in[2];
  const float* wgs  = (const float*)d_in[4];
  const float* ags  = (const float*)d_in[5];

  const int N = in_sizes[2];            // 4096
  const int K = in_sizes[1] / N;        // 4096
  const int M = in_sizes[0] / K;        // 8192
  const int kg = K / 32;                // 128

  unsigned char* aq  = (unsigned char*)d_ws;
  unsigned char* bq  = aq + (size_t)M * (K / 2);
  unsigned char* asc = bq + (size_t)N * (K / 2);
  unsigned char* bsc = asc + (size_t)M * kg;

  const int xg = in_sizes[0] / 32;
  const int wg = in_sizes[1] / 32;
  quant_pack_fp4<<<dim3((xg + 255) / 256), dim3(256), 0, stream>>>(x, aq, asc, ags, xg, M, kg);
  quant_pack_fp4<<<dim3((wg + 255) / 256), dim3(256), 0, stream>>>(wgt, bq, bsc, wgs, wg, N, kg);

  dim3 grid((M / 128) * (N / 128));
  gemm128_fp4<<<grid, dim3(256), 0, stream>>>(aq, bq, asc, bsc, (float*)d_out, bias,
                                              ags, wgs, M, N, K);
}